// Round 1
// 392.004 us; speedup vs baseline: 1.4503x; 1.4503x over previous
//
#include <hip/hip_runtime.h>

#define NB    256               // batch
#define NT    512               // time steps
#define NF    33                // features incl. flag channel
#define BOND  64
#define NOUT  32
#define TC    64                // chunk length (chain steps per block)
#define NCH   (NT / TC)         // 8 chunks per batch
#define MSTR  4104              // Mb row stride in f16 (4096 + 8: bank spread, keeps 16B align)

typedef _Float16 f16x8 __attribute__((ext_vector_type(8)));
typedef float    f32x4 __attribute__((ext_vector_type(4)));

// ---------------------------------------------------------------------------
// Phase 0: pack core channels f=1..32 into f16 MFMA-fragment order.
// For n-tile nt (16 columns n = nt*16+c, n=(i,j) flattened i*64+j), lane l
// (g=l>>4, c=l&15), slot m: cfrag[(nt*64+l)*8+m] = core[i][1+g*8+m][j].
// Used as the A-operand (C^T tile: rows=n, k=f') of the formation MFMA.
// ---------------------------------------------------------------------------
__global__ __launch_bounds__(64) void pack_cfrag(const float* __restrict__ core,
                                                 _Float16* __restrict__ cfrag)
{
    int tid = blockIdx.x * 64 + threadIdx.x;      // 0 .. 16383
    int nt = tid >> 6, l = tid & 63;
    int g = l >> 4, c = l & 15;
    int n = nt * 16 + c, i = n >> 6, j = n & 63;
    const float* src = core + (size_t)i * (NF * BOND) + (size_t)(1 + g * 8) * BOND + j;
    f16x8 v;
    #pragma unroll
    for (int m = 0; m < 8; ++m) v[m] = (_Float16)src[(size_t)m * BOND];
    *(f16x8*)(cfrag + (size_t)tid * 8) = v;
}

// ---------------------------------------------------------------------------
// Phase 1: per (batch, chunk) compute P = prod_{t in chunk} M_t, M_t = x0*I + sum_f x_f C_f.
// 8 waves. Formation: 16 M's at a time via mfma(C^T-tile, X^T) -> Mb (LDS, f16,
// transposed+swizzled: M[i][j] stored at [t'][j*64 + (i ^ ((j&7)<<3))]).
// Chain: P(16x32 per wave) = P @ M_t, A/B frags are conflict-free ds_read_b128.
// ---------------------------------------------------------------------------
__global__ __launch_bounds__(512, 1) void chunk_prod(const float* __restrict__ x,
                                                     const _Float16* __restrict__ cfrag,
                                                     float* __restrict__ Pout)
{
    const int tid = (int)threadIdx.x;
    const int l = tid & 63, w = tid >> 6;         // 8 waves
    const int g = l >> 4, c = l & 15;
    const int ch = (int)blockIdx.x, b = (int)blockIdx.y;
    const int t0 = ch * TC;

    __shared__ __align__(16) _Float16 Xl[TC][40]; // x features f'=0..31 (pad to 40)
    __shared__ float x0l[TC];                     // flag channel (f=0)
    __shared__ __align__(16) _Float16 Mb[16 * MSTR];
    __shared__ __align__(16) _Float16 Pb[2 * 4096];

    // ---- stage x chunk (coalesced f32 -> LDS f16 / f32 flag) ----
    const float* xb = x + (size_t)b * (NT * NF) + (size_t)t0 * NF;
    for (int idx = tid; idx < TC * NF; idx += 512) {
        int t = idx / NF, f = idx - t * NF;
        float v = xb[idx];
        if (f == 0) x0l[t] = v;
        else        Xl[t][f - 1] = (_Float16)v;
    }
    // ---- P = I (swizzled f16 layout: [row][col ^ ((row&7)<<3)]) ----
    for (int idx = tid; idx < 4096; idx += 512) {
        int row = idx >> 6, col = idx & 63;
        Pb[row * 64 + (col ^ ((row & 7) << 3))] = (row == col) ? (_Float16)1.f : (_Float16)0.f;
    }
    __syncthreads();

    const int rb = (w >> 1) << 4;                 // wave's P row block: 0/16/32/48
    const int cb = (w & 1) << 5;                  // wave's P col block: 0/32
    const int sw = (c & 7) << 3;                  // row-XOR for all chain reads (rows == c mod 8)
    int pcur = 0;

    #pragma unroll 1
    for (int fr = 0; fr < 4; ++fr) {
        // ======== formation of M for t' = 0..15 (lane's t' = c) ========
        // D'[n_local, t'] = (C^T @ X^T): A = cfrag tile, B = X^T fragment.
        f16x8 xa = *(const f16x8*)&Xl[fr * 16 + c][g * 8];   // X[t'=c][f'=g*8+m]
        float x0v = x0l[fr * 16 + c];
        const _Float16* cf = cfrag + ((size_t)(w * 32) * 64 + l) * 8;
        #pragma unroll 4
        for (int q = 0; q < 32; ++q) {            // this wave's 32 n-tiles
            int nt = w * 32 + q;
            f16x8 ca = *(const f16x8*)(cf + (size_t)q * 512);
            f32x4 zero = {0.f, 0.f, 0.f, 0.f};
            f32x4 d = __builtin_amdgcn_mfma_f32_16x16x32_f16(ca, xa, zero, 0, 0, 0);
            int i  = nt >> 2;                     // fixed per tile
            int jb = (nt & 3) << 4;
            #pragma unroll
            for (int r = 0; r < 4; ++r) {         // D rows: n_local = g*4+r
                int j = jb + g * 4 + r;
                float dv = d[r];
                if (j == i) dv += x0v;            // x0 * I (flag channel, exact f32 add)
                Mb[c * MSTR + j * 64 + (i ^ ((j & 7) << 3))] = (_Float16)dv;
            }
        }
        __syncthreads();

        // ======== chain 16 steps: P <- P @ M_s ========
        #pragma unroll 1
        for (int s = 0; s < 16; ++s) {
            const _Float16* Ms = &Mb[s * MSTR];
            const _Float16* Ps = &Pb[pcur * 4096];
            const int arow = rb + c;
            f16x8 a0  = *(const f16x8*)&Ps[arow * 64 + ((g * 8) ^ sw)];
            f16x8 a1  = *(const f16x8*)&Ps[arow * 64 + ((32 + g * 8) ^ sw)];
            f16x8 b00 = *(const f16x8*)&Ms[(cb + c) * 64      + ((g * 8)      ^ sw)];
            f16x8 b01 = *(const f16x8*)&Ms[(cb + c) * 64      + ((32 + g * 8) ^ sw)];
            f16x8 b10 = *(const f16x8*)&Ms[(cb + 16 + c) * 64 + ((g * 8)      ^ sw)];
            f16x8 b11 = *(const f16x8*)&Ms[(cb + 16 + c) * 64 + ((32 + g * 8) ^ sw)];
            f32x4 acc0 = {0.f, 0.f, 0.f, 0.f}, acc1 = {0.f, 0.f, 0.f, 0.f};
            acc0 = __builtin_amdgcn_mfma_f32_16x16x32_f16(a0, b00, acc0, 0, 0, 0);
            acc0 = __builtin_amdgcn_mfma_f32_16x16x32_f16(a1, b01, acc0, 0, 0, 0);
            acc1 = __builtin_amdgcn_mfma_f32_16x16x32_f16(a0, b10, acc1, 0, 0, 0);
            acc1 = __builtin_amdgcn_mfma_f32_16x16x32_f16(a1, b11, acc1, 0, 0, 0);

            _Float16* Pn = &Pb[(pcur ^ 1) * 4096];
            #pragma unroll
            for (int r = 0; r < 4; ++r) {         // D rows: R = rb + g*4 + r, cols cb(+16)+c
                int R = rb + g * 4 + r;
                int sP = (R & 7) << 3;
                Pn[R * 64 + ((cb + c) ^ sP)]      = (_Float16)acc0[r];
                Pn[R * 64 + ((cb + 16 + c) ^ sP)] = (_Float16)acc1[r];
            }
            if (fr == 3 && s == 15) {             // final product in f32 (pre-rounding)
                float* Po = Pout + ((size_t)(b * NCH + ch)) * 4096;
                #pragma unroll
                for (int r = 0; r < 4; ++r) {
                    int R = rb + g * 4 + r;
                    Po[R * 64 + cb + c]      = acc0[r];
                    Po[R * 64 + cb + 16 + c] = acc1[r];
                }
            }
            __syncthreads();
            pcur ^= 1;
        }
    }
}

// ---------------------------------------------------------------------------
// Phase 2: per batch, v = alpha; v = v @ P_c for c=0..7; out = v @ output_core.
// ---------------------------------------------------------------------------
__global__ __launch_bounds__(64) void combine(const float* __restrict__ P,
                                              const float* __restrict__ alpha,
                                              const float* __restrict__ oc,
                                              float* __restrict__ out)
{
    const int b = (int)blockIdx.x, j = (int)threadIdx.x;   // 64 lanes
    __shared__ float vb[BOND];
    float v = alpha[j];
    for (int ch = 0; ch < NCH; ++ch) {
        vb[j] = v;
        __syncthreads();
        const float* Pc = P + ((size_t)(b * NCH + ch)) * 4096;
        float s = 0.f;
        #pragma unroll 8
        for (int i = 0; i < BOND; ++i) s = fmaf(vb[i], Pc[i * 64 + j], s);
        __syncthreads();
        v = s;
    }
    vb[j] = v;
    __syncthreads();
    if (j < NOUT) {
        float s = 0.f;
        #pragma unroll 8
        for (int i = 0; i < BOND; ++i) s = fmaf(vb[i], oc[i * NOUT + j], s);
        out[b * NOUT + j] = s;
    }
}

extern "C" void kernel_launch(void* const* d_in, const int* in_sizes, int n_in,
                              void* d_out, int out_size, void* d_ws, size_t ws_size,
                              hipStream_t stream)
{
    const float* x     = (const float*)d_in[0];  // (256, 512, 33) f32
    const float* core  = (const float*)d_in[1];  // (64, 33, 64) f32
    const float* alpha = (const float*)d_in[2];  // (64,) f32
    const float* oc    = (const float*)d_in[3];  // (64, 32) f32
    float* out = (float*)d_out;                  // (256, 32) f32

    // workspace: [cfrag f16: 262144 B][P f32: 256*8*4096*4 = 33554432 B] = 33.8 MB
    _Float16* cfrag = (_Float16*)d_ws;
    float*    P     = (float*)((char*)d_ws + 262144);

    pack_cfrag<<<dim3(256), dim3(64), 0, stream>>>(core, cfrag);
    chunk_prod<<<dim3(NCH, NB), dim3(512), 0, stream>>>(x, cfrag, P);
    combine<<<dim3(NB), dim3(64), 0, stream>>>(P, alpha, oc, out);
}

// Round 5
// 286.942 us; speedup vs baseline: 1.9813x; 1.3661x over previous
//
#include <hip/hip_runtime.h>

#define NB    256               // batch
#define NT    512               // time steps
#define NF    33                // features incl. flag channel
#define BOND  64
#define NOUT  32
#define TC    64                // chunk length
#define NCH   (NT / TC)         // 8 chunks per batch
#define MSTR  4104              // f16 stride per staged M^T slice (4096 + 8 -> bank skew)

typedef _Float16 f16x4 __attribute__((ext_vector_type(4)));
typedef _Float16 f16x8 __attribute__((ext_vector_type(8)));
typedef float    f32x4 __attribute__((ext_vector_type(4)));

// ---------------------------------------------------------------------------
// Phase 0: pack core channels f=1..32 into f16 MFMA A-fragment order with
// COLUMN-MAJOR flattening n' = j*64 + i (so formation D-rows walk i, not j):
//   cfrag[(nt*64 + l)*8 + m] = core[i][1+g*8+m][j],  n' = nt*16 + (l&15),
//   i = n' & 63, j = n' >> 6,  g = l>>4.
// ---------------------------------------------------------------------------
__global__ __launch_bounds__(64) void pack_cfrag(const float* __restrict__ core,
                                                 _Float16* __restrict__ cfrag)
{
    int tid = blockIdx.x * 64 + threadIdx.x;      // 0 .. 16383
    int nt = tid >> 6, l = tid & 63;
    int g = l >> 4, c = l & 15;
    int n = nt * 16 + c;
    int i = n & 63, j = n >> 6;                   // column-major flatten
    const float* src = core + (size_t)i * (NF * BOND) + (size_t)(1 + g * 8) * BOND + j;
    f16x8 v;
    #pragma unroll
    for (int m = 0; m < 8; ++m) v[m] = (_Float16)src[(size_t)m * BOND];
    *(f16x8*)(cfrag + (size_t)tid * 8) = v;
}

// ---------------------------------------------------------------------------
// Phase 1 (HYBRID): formation writes M^T[j][i] row-runs with ONE ds_write_b64
// per tile (conflict-free); chain is the round-1 hardware-verified code,
// verbatim: P row-major [row][col ^ ((row&7)<<3)], A = P rows, B = M^T rows,
// P' scalar writes, P' = P @ M_s.
// ---------------------------------------------------------------------------
__global__ __launch_bounds__(512, 1) void chunk_prod(const float* __restrict__ x,
                                                     const _Float16* __restrict__ cfrag,
                                                     float* __restrict__ Pout)
{
    __shared__ __align__(16) _Float16 PB[2][64 * 64];
    __shared__ __align__(16) _Float16 Mb[16 * MSTR];
    __shared__ __align__(16) _Float16 Xl[TC][32];
    __shared__ float x0l[TC];

    const int tid = (int)threadIdx.x;
    const int l = tid & 63, w = tid >> 6;         // 8 waves
    const int g = l >> 4, c = l & 15;
    const int ch = (int)blockIdx.x, b = (int)blockIdx.y;

    // ---- stage x chunk ----
    const float* xb = x + (size_t)b * (NT * NF) + (size_t)(ch * TC) * NF;
    for (int idx = tid; idx < TC * NF; idx += 512) {
        int t = idx / NF, f = idx - t * NF;
        float v = xb[idx];
        if (f == 0) x0l[t] = v;
        else        Xl[t][f - 1] = (_Float16)v;
    }
    // ---- P = I (row-major, swizzled) — round-1 verbatim ----
    for (int idx = tid; idx < 4096; idx += 512) {
        int row = idx >> 6, col = idx & 63;
        PB[0][row * 64 + (col ^ ((row & 7) << 3))] = (row == col) ? (_Float16)1.f : (_Float16)0.f;
    }

    // ---- cache this wave's 32 cfrag tiles in registers (read once) ----
    f16x8 creg[32];
    {
        const _Float16* cf = cfrag + (size_t)w * 16384 + (size_t)l * 8;
        #pragma unroll
        for (int q = 0; q < 32; ++q) creg[q] = *(const f16x8*)(cf + (size_t)q * 512);
    }
    __syncthreads();

    const int sw = (c & 7) << 3;                  // row-XOR for all chain reads
    const int rb = (w >> 1) << 4;                 // wave's P row block: 0/16/32/48
    const int cb = (w & 1) << 5;                  // wave's P col block: 0/32
    const int arow = rb + c;

    int pcur = 0;
    #pragma unroll 1
    for (int fr = 0; fr < 4; ++fr) {
        // ======== formation: M^T slices for t' = fr*16 + c (vector write) ========
        f16x8 xa  = *(const f16x8*)&Xl[fr * 16 + c][g * 8];
        float x0v = x0l[fr * 16 + c];
        #pragma unroll
        for (int q = 0; q < 32; ++q) {
            int nt = w * 32 + q;
            f32x4 zero = {0.f, 0.f, 0.f, 0.f};
            f32x4 d = __builtin_amdgcn_mfma_f32_16x16x32_f16(creg[q], xa, zero, 0, 0, 0);
            // lane holds M[i0..i0+3][j], i0 = (nt&3)*16 + g*4, j = nt>>2
            int j  = nt >> 2;
            int i0 = ((nt & 3) << 4) + (g << 2);
            int dr = j - i0;                      // diag slot if 0..3
            f16x4 mv;
            mv[0] = (_Float16)((dr == 0) ? d[0] + x0v : d[0]);   // RNE, as round 1
            mv[1] = (_Float16)((dr == 1) ? d[1] + x0v : d[1]);
            mv[2] = (_Float16)((dr == 2) ? d[2] + x0v : d[2]);
            mv[3] = (_Float16)((dr == 3) ? d[3] + x0v : d[3]);
            *(f16x4*)(&Mb[c * MSTR + (j << 6) + (i0 ^ ((j & 7) << 3))]) = mv;
        }
        __syncthreads();

        // ======== chain 16 steps: P <- P @ M_s (round-1 verbatim) ========
        #pragma unroll 4
        for (int s = 0; s < 16; ++s) {
            const _Float16* Ms = &Mb[s * MSTR];
            const _Float16* Ps = &PB[pcur][0];
            f16x8 a0  = *(const f16x8*)&Ps[arow * 64 + ((g * 8)      ^ sw)];
            f16x8 a1  = *(const f16x8*)&Ps[arow * 64 + ((32 + g * 8) ^ sw)];
            f16x8 b00 = *(const f16x8*)&Ms[(cb + c) * 64      + ((g * 8)      ^ sw)];
            f16x8 b01 = *(const f16x8*)&Ms[(cb + c) * 64      + ((32 + g * 8) ^ sw)];
            f16x8 b10 = *(const f16x8*)&Ms[(cb + 16 + c) * 64 + ((g * 8)      ^ sw)];
            f16x8 b11 = *(const f16x8*)&Ms[(cb + 16 + c) * 64 + ((32 + g * 8) ^ sw)];
            f32x4 acc0 = {0.f, 0.f, 0.f, 0.f}, acc1 = {0.f, 0.f, 0.f, 0.f};
            acc0 = __builtin_amdgcn_mfma_f32_16x16x32_f16(a0, b00, acc0, 0, 0, 0);
            acc0 = __builtin_amdgcn_mfma_f32_16x16x32_f16(a1, b01, acc0, 0, 0, 0);
            acc1 = __builtin_amdgcn_mfma_f32_16x16x32_f16(a0, b10, acc1, 0, 0, 0);
            acc1 = __builtin_amdgcn_mfma_f32_16x16x32_f16(a1, b11, acc1, 0, 0, 0);

            if (fr == 3 && s == 15) {             // final chunk product in f32
                float* Po = Pout + (size_t)(b * NCH + ch) * 4096;
                #pragma unroll
                for (int r = 0; r < 4; ++r) {
                    int R = rb + g * 4 + r;
                    Po[R * 64 + cb + c]      = acc0[r];
                    Po[R * 64 + cb + 16 + c] = acc1[r];
                }
            } else {
                _Float16* Pn = &PB[pcur ^ 1][0];
                #pragma unroll
                for (int r = 0; r < 4; ++r) {
                    int R = rb + g * 4 + r;
                    int sP = (R & 7) << 3;
                    Pn[R * 64 + ((cb + c) ^ sP)]      = (_Float16)acc0[r];
                    Pn[R * 64 + ((cb + 16 + c) ^ sP)] = (_Float16)acc1[r];
                }
            }
            __syncthreads();
            pcur ^= 1;
        }
    }
}

// ---------------------------------------------------------------------------
// Phase 2: per batch, v = alpha; v = v @ P_c for c=0..7; out = v @ output_core.
// ---------------------------------------------------------------------------
__global__ __launch_bounds__(64) void combine(const float* __restrict__ P,
                                              const float* __restrict__ alpha,
                                              const float* __restrict__ oc,
                                              float* __restrict__ out)
{
    const int b = (int)blockIdx.x, j = (int)threadIdx.x;   // 64 lanes
    __shared__ float vb[BOND];
    float v = alpha[j];
    for (int ch = 0; ch < NCH; ++ch) {
        vb[j] = v;
        __syncthreads();
        const float* Pc = P + (size_t)(b * NCH + ch) * 4096;
        float s = 0.f;
        #pragma unroll 8
        for (int i = 0; i < BOND; ++i) s = fmaf(vb[i], Pc[i * 64 + j], s);
        __syncthreads();
        v = s;
    }
    vb[j] = v;
    __syncthreads();
    if (j < NOUT) {
        float s = 0.f;
        #pragma unroll 8
        for (int i = 0; i < BOND; ++i) s = fmaf(vb[i], oc[i * NOUT + j], s);
        out[b * NOUT + j] = s;
    }
}

extern "C" void kernel_launch(void* const* d_in, const int* in_sizes, int n_in,
                              void* d_out, int out_size, void* d_ws, size_t ws_size,
                              hipStream_t stream)
{
    const float* x     = (const float*)d_in[0];  // (256, 512, 33) f32
    const float* core  = (const float*)d_in[1];  // (64, 33, 64) f32
    const float* alpha = (const float*)d_in[2];  // (64,) f32
    const float* oc    = (const float*)d_in[3];  // (64, 32) f32
    float* out = (float*)d_out;                  // (256, 32) f32

    // workspace: [cfrag f16: 262144 B][P f32: 256*8*4096*4 = 33554432 B]
    _Float16* cfrag = (_Float16*)d_ws;
    float*    P     = (float*)((char*)d_ws + 262144);

    pack_cfrag<<<dim3(256), dim3(64), 0, stream>>>(core, cfrag);
    chunk_prod<<<dim3(NCH, NB), dim3(512), 0, stream>>>(x, cfrag, P);
    combine<<<dim3(NB), dim3(64), 0, stream>>>(P, alpha, oc, out);
}

// Round 6
// 244.709 us; speedup vs baseline: 2.3232x; 1.1726x over previous
//
#include <hip/hip_runtime.h>

#define NB    256               // batch
#define NT    512               // time steps
#define NF    33                // features incl. flag channel
#define BOND  64
#define NOUT  32
#define TC    64                // chunk length
#define NCH   (NT / TC)         // 8 chunks per batch
#define MSTR  4104              // f16 stride per staged M^T slice (4096 + 8 -> bank skew)

typedef _Float16 f16x4 __attribute__((ext_vector_type(4)));
typedef _Float16 f16x8 __attribute__((ext_vector_type(8)));
typedef float    f32x4 __attribute__((ext_vector_type(4)));

// ---------------------------------------------------------------------------
// Phase 0: pack core channels f=1..32 into f16 MFMA A-fragment order with
// COLUMN-MAJOR flattening n' = j*64 + i (so formation D-rows walk i, not j):
//   cfrag[(nt*64 + l)*8 + m] = core[i][1+g*8+m][j],  n' = nt*16 + (l&15),
//   i = n' & 63, j = n' >> 6,  g = l>>4.
// ---------------------------------------------------------------------------
__global__ __launch_bounds__(64) void pack_cfrag(const float* __restrict__ core,
                                                 _Float16* __restrict__ cfrag)
{
    int tid = blockIdx.x * 64 + threadIdx.x;      // 0 .. 16383
    int nt = tid >> 6, l = tid & 63;
    int g = l >> 4, c = l & 15;
    int n = nt * 16 + c;
    int i = n & 63, j = n >> 6;                   // column-major flatten
    const float* src = core + (size_t)i * (NF * BOND) + (size_t)(1 + g * 8) * BOND + j;
    f16x8 v;
    #pragma unroll
    for (int m = 0; m < 8; ++m) v[m] = (_Float16)src[(size_t)m * BOND];
    *(f16x8*)(cfrag + (size_t)tid * 8) = v;
}

// ---------------------------------------------------------------------------
// Phase 1: formation writes M^T[j][i] row-runs with ONE ds_write_b64 per tile
// (conflict-free); chain reads are round-1 verified verbatim; chain MFMAs use
// SWAPPED operand slots (A <- M^T rows, B <- P rows) so D = P'^T tiles: lane
// (g,c) holds P'[rb+c][cb+4g..+3] -> vector b64 P' writes, f32x4 Pout writes.
// ---------------------------------------------------------------------------
__global__ __launch_bounds__(512, 1) void chunk_prod(const float* __restrict__ x,
                                                     const _Float16* __restrict__ cfrag,
                                                     float* __restrict__ Pout)
{
    __shared__ __align__(16) _Float16 PB[2][64 * 64];
    __shared__ __align__(16) _Float16 Mb[16 * MSTR];
    __shared__ __align__(16) _Float16 Xl[TC][32];
    __shared__ float x0l[TC];

    const int tid = (int)threadIdx.x;
    const int l = tid & 63, w = tid >> 6;         // 8 waves
    const int g = l >> 4, c = l & 15;
    const int ch = (int)blockIdx.x, b = (int)blockIdx.y;

    // ---- stage x chunk ----
    const float* xb = x + (size_t)b * (NT * NF) + (size_t)(ch * TC) * NF;
    for (int idx = tid; idx < TC * NF; idx += 512) {
        int t = idx / NF, f = idx - t * NF;
        float v = xb[idx];
        if (f == 0) x0l[t] = v;
        else        Xl[t][f - 1] = (_Float16)v;
    }
    // ---- P = I (row-major, swizzled) ----
    for (int idx = tid; idx < 4096; idx += 512) {
        int row = idx >> 6, col = idx & 63;
        PB[0][row * 64 + (col ^ ((row & 7) << 3))] = (row == col) ? (_Float16)1.f : (_Float16)0.f;
    }

    // ---- cache this wave's 32 cfrag tiles in registers (read once) ----
    f16x8 creg[32];
    {
        const _Float16* cf = cfrag + (size_t)w * 16384 + (size_t)l * 8;
        #pragma unroll
        for (int q = 0; q < 32; ++q) creg[q] = *(const f16x8*)(cf + (size_t)q * 512);
    }
    __syncthreads();

    const int sw = (c & 7) << 3;                  // row-XOR for all chain reads
    const int rb = (w >> 1) << 4;                 // wave's P row block: 0/16/32/48
    const int cb = (w & 1) << 5;                  // wave's P col block: 0/32
    const int arow = rb + c;
    const int wcol = (cb + 4 * g) ^ sw;           // P' write col base (row = arow)

    int pcur = 0;
    #pragma unroll 1
    for (int fr = 0; fr < 4; ++fr) {
        // ======== formation: M^T slices for t' = fr*16 + c (vector write) ========
        f16x8 xa  = *(const f16x8*)&Xl[fr * 16 + c][g * 8];
        float x0v = x0l[fr * 16 + c];
        #pragma unroll
        for (int q = 0; q < 32; ++q) {
            int nt = w * 32 + q;
            f32x4 zero = {0.f, 0.f, 0.f, 0.f};
            f32x4 d = __builtin_amdgcn_mfma_f32_16x16x32_f16(creg[q], xa, zero, 0, 0, 0);
            // lane holds M[i0..i0+3][j], i0 = (nt&3)*16 + g*4, j = nt>>2
            int j  = nt >> 2;
            int i0 = ((nt & 3) << 4) + (g << 2);
            int dr = j - i0;                      // diag slot if 0..3
            f16x4 mv;
            mv[0] = (_Float16)((dr == 0) ? d[0] + x0v : d[0]);   // RNE
            mv[1] = (_Float16)((dr == 1) ? d[1] + x0v : d[1]);
            mv[2] = (_Float16)((dr == 2) ? d[2] + x0v : d[2]);
            mv[3] = (_Float16)((dr == 3) ? d[3] + x0v : d[3]);
            *(f16x4*)(&Mb[c * MSTR + (j << 6) + (i0 ^ ((j & 7) << 3))]) = mv;
        }
        __syncthreads();

        // ======== chain 16 steps: P'^T tiles = M^T-tile (A) x P^T-tile (B) ========
        #pragma unroll 4
        for (int s = 0; s < 16; ++s) {
            const _Float16* Ms = &Mb[s * MSTR];
            const _Float16* Ps = &PB[pcur][0];
            f16x8 a0  = *(const f16x8*)&Ps[arow * 64 + ((g * 8)      ^ sw)];
            f16x8 a1  = *(const f16x8*)&Ps[arow * 64 + ((32 + g * 8) ^ sw)];
            f16x8 b00 = *(const f16x8*)&Ms[(cb + c) * 64      + ((g * 8)      ^ sw)];
            f16x8 b01 = *(const f16x8*)&Ms[(cb + c) * 64      + ((32 + g * 8) ^ sw)];
            f16x8 b10 = *(const f16x8*)&Ms[(cb + 16 + c) * 64 + ((g * 8)      ^ sw)];
            f16x8 b11 = *(const f16x8*)&Ms[(cb + 16 + c) * 64 + ((32 + g * 8) ^ sw)];
            f32x4 acc0 = {0.f, 0.f, 0.f, 0.f}, acc1 = {0.f, 0.f, 0.f, 0.f};
            // swapped slots: D = (M^T rows) x (P rows as P^T cols) = P'^T tile
            acc0 = __builtin_amdgcn_mfma_f32_16x16x32_f16(b00, a0, acc0, 0, 0, 0);
            acc0 = __builtin_amdgcn_mfma_f32_16x16x32_f16(b01, a1, acc0, 0, 0, 0);
            acc1 = __builtin_amdgcn_mfma_f32_16x16x32_f16(b10, a0, acc1, 0, 0, 0);
            acc1 = __builtin_amdgcn_mfma_f32_16x16x32_f16(b11, a1, acc1, 0, 0, 0);
            // lane (g,c): acc0 = P'[arow][cb+4g .. +3], acc1 = same row, cols +16

            if (fr == 3 && s == 15) {             // final chunk product in f32
                float* Po = Pout + (size_t)(b * NCH + ch) * 4096;
                *(f32x4*)(Po + arow * 64 + cb + 4 * g)      = acc0;
                *(f32x4*)(Po + arow * 64 + cb + 16 + 4 * g) = acc1;
            } else {
                _Float16* Pn = &PB[pcur ^ 1][0];
                f16x4 v0, v1;
                v0[0] = (_Float16)acc0[0]; v0[1] = (_Float16)acc0[1];   // RNE, as before
                v0[2] = (_Float16)acc0[2]; v0[3] = (_Float16)acc0[3];
                v1[0] = (_Float16)acc1[0]; v1[1] = (_Float16)acc1[1];
                v1[2] = (_Float16)acc1[2]; v1[3] = (_Float16)acc1[3];
                *(f16x4*)(Pn + arow * 64 + wcol)        = v0;
                *(f16x4*)(Pn + arow * 64 + (wcol ^ 16)) = v1;
            }
            __syncthreads();
            pcur ^= 1;
        }
    }
}

// ---------------------------------------------------------------------------
// Phase 2: per batch, v = alpha; v = v @ P_c for c=0..7; out = v @ output_core.
// 256 threads: lane j of quarter q sums i = 16q..16q+15, tree-reduced via LDS.
// ---------------------------------------------------------------------------
__global__ __launch_bounds__(256) void combine(const float* __restrict__ P,
                                               const float* __restrict__ alpha,
                                               const float* __restrict__ oc,
                                               float* __restrict__ out)
{
    const int b = (int)blockIdx.x;
    const int tid = (int)threadIdx.x, j = tid & 63, q = tid >> 6;   // q = 0..3
    __shared__ float vb[BOND];
    __shared__ float ps[4][BOND];
    if (tid < BOND) vb[tid] = alpha[tid];
    __syncthreads();
    for (int ch = 0; ch < NCH; ++ch) {
        const float* Pc = P + (size_t)(b * NCH + ch) * 4096;
        float s = 0.f;
        #pragma unroll
        for (int k = 0; k < 16; ++k) {
            int i = q * 16 + k;
            s = fmaf(vb[i], Pc[i * 64 + j], s);
        }
        ps[q][j] = s;
        __syncthreads();
        if (q == 0) vb[j] = (ps[0][j] + ps[1][j]) + (ps[2][j] + ps[3][j]);
        __syncthreads();
    }
    if (tid < NOUT) {
        float s = 0.f;
        #pragma unroll 8
        for (int i = 0; i < BOND; ++i) s = fmaf(vb[i], oc[i * NOUT + tid], s);
        out[b * NOUT + tid] = s;
    }
}

extern "C" void kernel_launch(void* const* d_in, const int* in_sizes, int n_in,
                              void* d_out, int out_size, void* d_ws, size_t ws_size,
                              hipStream_t stream)
{
    const float* x     = (const float*)d_in[0];  // (256, 512, 33) f32
    const float* core  = (const float*)d_in[1];  // (64, 33, 64) f32
    const float* alpha = (const float*)d_in[2];  // (64,) f32
    const float* oc    = (const float*)d_in[3];  // (64, 32) f32
    float* out = (float*)d_out;                  // (256, 32) f32

    // workspace: [cfrag f16: 262144 B][P f32: 256*8*4096*4 = 33554432 B]
    _Float16* cfrag = (_Float16*)d_ws;
    float*    P     = (float*)((char*)d_ws + 262144);

    pack_cfrag<<<dim3(256), dim3(64), 0, stream>>>(core, cfrag);
    chunk_prod<<<dim3(NCH, NB), dim3(512), 0, stream>>>(x, cfrag, P);
    combine<<<dim3(NB), dim3(256), 0, stream>>>(P, alpha, oc, out);
}